// Round 11
// baseline (180.692 us; speedup 1.0000x reference)
//
#include <hip/hip_runtime.h>
#include <hip/hip_bf16.h>

// ChildSum Tree-LSTM, MI355X. B=32, N=511 full binary heap (children of i:
// 2i-511, 2i-512; leaves i<256; root 510). v11 = v10 skeleton +
//  - global_load_lds (width=16) weight staging, swizzle moved to SOURCE addr
//    (linear LDS dest; XOR involution => read swizzle unchanged)
//  - task loops: xproj 2 tasks/wave (1024 blocks), level_h d7 2 tasks/wave (512)
// Measured session facts:
//  - r7/r8: single-kernel cross-block sync (grid.sync OR spin+fence) ~13x slow
//    (device-scope fence flushes per-XCD L2). Per-level chain is the skeleton.
//  - r9: exceeding launch_bounds VGPR cap spills (WRITE_SIZE 10x). Keep 1 task
//    live per wave, 6 accumulators, phase-local A prefetch.

#define NN 511
#define BB 32
#define DD 256

typedef __attribute__((ext_vector_type(8))) short short8;
typedef __attribute__((ext_vector_type(4))) short short4v;
typedef __attribute__((ext_vector_type(4))) float f32x4;

#define MFMA __builtin_amdgcn_mfma_f32_16x16x32_bf16

typedef __attribute__((address_space(3))) void lds_void_t;
typedef const __attribute__((address_space(1))) void glob_void_t;

// ---- ws layout (bytes) ----
#define OFF_XBF   0UL            // [511*32][256] bf16 = 8,372,224
#define OFF_HBF   8372224UL      // [511*32][256] bf16 = 8,372,224
#define OFF_CBUF  16744448UL     // [511*32][256] f32  = 16,744,448
#define OFF_WCAT  33488896UL     // [1024][512] bf16   = 1,048,576 (rows i,o,u,f x256; cols 0:256 Wx, 256:512 Wh)
#define OFF_BIAS  34537472UL     // [1024] f32 = bx + bh
// total ~34.5 MB

__device__ __forceinline__ short f2bf(float f) {
    union { float f; unsigned int u; } v; v.f = f;
    unsigned int r = (v.u + 0x7FFFu + ((v.u >> 16) & 1u)) >> 16;  // RNE
    return (short)(unsigned short)r;
}
__device__ __forceinline__ float sigmf(float x) { return 1.0f / (1.0f + __expf(-x)); }
__device__ __forceinline__ float tanhc(float x) {
    x = fminf(fmaxf(x, -15.f), 15.f);
    float e = __expf(2.f * x);
    return (e - 1.f) / (e + 1.f);
}

// ---- merged prep: x -> bf16 node-major, weights -> wcat bf16, bias ----
__global__ void prep_all(const float* __restrict__ inp,
                         const float* __restrict__ Wix, const float* __restrict__ Wih,
                         const float* __restrict__ Wfx, const float* __restrict__ Wfh,
                         const float* __restrict__ bix, const float* __restrict__ bih,
                         const float* __restrict__ bfx, const float* __restrict__ bfh,
                         short* __restrict__ xbf, short* __restrict__ wcat,
                         float* __restrict__ bias) {
    const int tid = threadIdx.x;
    for (int v = blockIdx.x; v < 4088 + 2048; v += gridDim.x) {
        if (v < 4088) {                    // prep_x: 4088*256 == 511*32*64 float4s
            int idx = v * 256 + tid;
            int n = idx / (BB * 64);
            int rem = idx - n * (BB * 64);
            int b = rem >> 6;
            int c4 = rem & 63;
            float4 w = ((const float4*)(inp + ((long)b * NN + n) * DD))[c4];
            short4v sv = { f2bf(w.x), f2bf(w.y), f2bf(w.z), f2bf(w.w) };
            *(short4v*)(xbf + (long)idx * 4) = sv;
        } else {                           // prep_w: 2048*256 == 1024*512
            int t = (v - 4088) * 256 + tid;
            int row = t >> 9, c = t & 511;
            float w;
            if (c < 256) w = (row < 768) ? Wix[row * 256 + c] : Wfx[(row - 768) * 256 + c];
            else         w = (row < 768) ? Wih[row * 256 + (c - 256)]
                                         : Wfh[(row - 768) * 256 + (c - 256)];
            wcat[t] = f2bf(w);
            if (c == 0)
                bias[row] = (row < 768) ? (bix[row] + bih[row])
                                        : (bfx[row - 768] + bfh[row - 768]);
        }
    }
}

// MFMA 16x16x32 bf16 mapping (m89/m91-verified):
//   A[row=lane&15][k=(lane>>4)*8+j], B[k][col=lane&15], D[row=(lane>>4)*4+r][col=lane&15]

// Leaf-only x-projection + gate epilogue. Stages 3 streams x K=256 = 24 KiB LDS
// via global_load_lds (source pre-swizzled, LDS linear; read swizzle = same XOR).
__global__ __launch_bounds__(256, 4) void xproj(
    const short* __restrict__ xbf, const short* __restrict__ wcat,
    const float* __restrict__ bias, short* __restrict__ hbf,
    float* __restrict__ cbuf, float* __restrict__ out, int ntasks) {
    __shared__ short lb[3 * 16 * 256];       // 24 KiB
    const int tid = threadIdx.x;
    const int mt = blockIdx.y;               // 16-col m-tile, 0..15
#pragma unroll
    for (int it = 0; it < 6; ++it) {         // 6*256 = 1536 short8 units
        const int u = it * 256 + tid;
        const int s = u >> 9;                // stream 0..2
        const int rr = (u >> 5) & 15;        // row in slice
        const int k = (u & 31) * 8;          // 0..255
        const short* src = wcat + ((long)(s * 256 + mt * 16 + rr) * 512
                                   + (k ^ ((rr & 7) << 3)));
        __builtin_amdgcn_global_load_lds((glob_void_t*)src,
            (lds_void_t*)(lb + (it * 256 + (tid >> 6) * 64) * 8), 16, 0, 0);
    }
    __syncthreads();

    const int lane = tid & 63;
    const int wid = tid >> 6;
    const int slot = blockIdx.x * 4 + wid;
    const int nslots = gridDim.x * 4;
    const int arow = lane & 15;
    const int kgrp = lane >> 4;
    const int m = mt * 16 + arow;
    const int swz = (arow & 7) << 3;
    const short* b0 = lb + (0 * 16 + arow) * 256;
    const short* b1 = lb + (1 * 16 + arow) * 256;
    const short* b2 = lb + (2 * 16 + arow) * 256;
    const float bi = bias[m], bo = bias[256 + m], bu = bias[512 + m];

    for (int rt = slot; rt < ntasks; rt += nslots) {
        const int node = rt >> 1;
        const int bh = rt & 1;

        const short* ap = xbf + ((long)rt * 16 + arow) * DD + kgrp * 8;
        short8 a[8];
#pragma unroll
        for (int ks = 0; ks < 8; ++ks) a[ks] = *(const short8*)(ap + ks * 32);

        f32x4 ai = {0.f, 0.f, 0.f, 0.f}, ao = ai, au = ai;
#pragma unroll
        for (int ks = 0; ks < 8; ++ks) {
            const int ko = (ks * 32 + kgrp * 8) ^ swz;
            ai = MFMA(a[ks], *(const short8*)(b0 + ko), ai, 0, 0, 0);
            ao = MFMA(a[ks], *(const short8*)(b1 + ko), ao, 0, 0, 0);
            au = MFMA(a[ks], *(const short8*)(b2 + ko), au, 0, 0, 0);
        }

#pragma unroll
        for (int r = 0; r < 4; ++r) {
            const int b = bh * 16 + kgrp * 4 + r;
            const float iv = sigmf(ai[r] + bi);
            const float ov = sigmf(ao[r] + bo);
            const float uv = tanhc(au[r] + bu);
            const float c = iv * uv;
            const float h = ov * tanhc(c);
            const long rowg = (long)node * BB + b;
            cbuf[rowg * DD + m] = c;
            hbf[rowg * DD + m] = f2bf(h);
            out[2 * BB * DD + ((long)b * NN + node) * DD + m] = h;
        }
    }
}

// Internal levels: fused K=512 GEMM ([x | h]), 64 KiB LDS via global_load_lds.
__global__ __launch_bounds__(256, 2) void level_h(
    const short* __restrict__ xbf, const short* __restrict__ wcat,
    const float* __restrict__ bias, short* __restrict__ hbf,
    float* __restrict__ cbuf, float* __restrict__ out, int istart, int ntasks) {
    __shared__ short lb[4 * 16 * 512];       // 64 KiB
    const int tid = threadIdx.x;
    const int mt = blockIdx.y;
#pragma unroll
    for (int it = 0; it < 16; ++it) {        // 16*256 = 4096 short8 units
        const int u = it * 256 + tid;
        const int s = u >> 10;               // stream 0..3
        const int rr = (u >> 6) & 15;        // row in slice
        const int k = (u & 63) * 8;          // 0..511
        const short* src = wcat + ((long)(s * 256 + mt * 16 + rr) * 512
                                   + (k ^ ((rr & 7) << 3)));
        __builtin_amdgcn_global_load_lds((glob_void_t*)src,
            (lds_void_t*)(lb + (it * 256 + (tid >> 6) * 64) * 8), 16, 0, 0);
    }
    __syncthreads();

    const int lane = tid & 63;
    const int wid = tid >> 6;
    const int slot = blockIdx.x * 4 + wid;
    const int nslots = gridDim.x * 4;
    const int arow = lane & 15;
    const int kgrp = lane >> 4;
    const int m = mt * 16 + arow;
    const int swz = (arow & 7) << 3;
    const short* b0 = lb + (0 * 16 + arow) * 512;
    const short* b1 = lb + (1 * 16 + arow) * 512;
    const short* b2 = lb + (2 * 16 + arow) * 512;
    const short* b3 = lb + (3 * 16 + arow) * 512;
    const float bi = bias[m], bo = bias[256 + m], bu = bias[512 + m], bf = bias[768 + m];

    for (int rt = slot; rt < ntasks; rt += nslots) {
        const int node = istart + (rt >> 1);
        const int bh = rt & 1;
        const int c0 = 2 * node - 511, c1 = 2 * node - 512;

        f32x4 ai = {0.f, 0.f, 0.f, 0.f}, ao = ai, au = ai, afx = ai, af0 = ai, af1 = ai;

        // ---- x phase: K cols 0..255, whole-K A prefetch (8 x short8) ----
        {
            const short* ap = xbf + ((long)(node * BB + bh * 16) + arow) * DD + kgrp * 8;
            short8 a[8];
#pragma unroll
            for (int ks = 0; ks < 8; ++ks) a[ks] = *(const short8*)(ap + ks * 32);
#pragma unroll
            for (int ks = 0; ks < 8; ++ks) {
                const int ko = (ks * 32 + kgrp * 8) ^ swz;
                ai = MFMA(a[ks], *(const short8*)(b0 + ko), ai, 0, 0, 0);
                ao = MFMA(a[ks], *(const short8*)(b1 + ko), ao, 0, 0, 0);
                au = MFMA(a[ks], *(const short8*)(b2 + ko), au, 0, 0, 0);
                afx = MFMA(a[ks], *(const short8*)(b3 + ko), afx, 0, 0, 0);
            }
        }
        // ---- h phase: K cols 256..511, both children whole-K (16 x short8) ----
        {
            const short* ap0 = hbf + ((long)(c0 * BB + bh * 16) + arow) * DD + kgrp * 8;
            const short* ap1 = hbf + ((long)(c1 * BB + bh * 16) + arow) * DD + kgrp * 8;
            short8 a0[8], a1[8];
#pragma unroll
            for (int ks = 0; ks < 8; ++ks) {
                a0[ks] = *(const short8*)(ap0 + ks * 32);
                a1[ks] = *(const short8*)(ap1 + ks * 32);
            }
#pragma unroll
            for (int ks = 0; ks < 8; ++ks) {
                const int ko = 256 + ((ks * 32 + kgrp * 8) ^ swz);
                short8 wi = *(const short8*)(b0 + ko);
                short8 wo = *(const short8*)(b1 + ko);
                short8 wu = *(const short8*)(b2 + ko);
                short8 wf = *(const short8*)(b3 + ko);
                ai = MFMA(a0[ks], wi, ai, 0, 0, 0);   // fp32 child-sum via accumulation
                ai = MFMA(a1[ks], wi, ai, 0, 0, 0);
                ao = MFMA(a0[ks], wo, ao, 0, 0, 0);
                ao = MFMA(a1[ks], wo, ao, 0, 0, 0);
                au = MFMA(a0[ks], wu, au, 0, 0, 0);
                au = MFMA(a1[ks], wu, au, 0, 0, 0);
                af0 = MFMA(a0[ks], wf, af0, 0, 0, 0); // per-child forget gates
                af1 = MFMA(a1[ks], wf, af1, 0, 0, 0);
            }
        }

#pragma unroll
        for (int r = 0; r < 4; ++r) {
            const int b = bh * 16 + kgrp * 4 + r;
            const float iv = sigmf(ai[r] + bi);
            const float ov = sigmf(ao[r] + bo);
            const float uv = tanhc(au[r] + bu);
            const float f0 = sigmf(afx[r] + af0[r] + bf);
            const float f1 = sigmf(afx[r] + af1[r] + bf);
            const float cc0 = cbuf[((long)c0 * BB + b) * DD + m];
            const float cc1 = cbuf[((long)c1 * BB + b) * DD + m];
            const float c = iv * uv + f0 * cc0 + f1 * cc1;
            const float h = ov * tanhc(c);
            const long rowg = (long)node * BB + b;
            cbuf[rowg * DD + m] = c;
            hbf[rowg * DD + m] = f2bf(h);
            out[2 * BB * DD + ((long)b * NN + node) * DD + m] = h;
            if (node == NN - 1) {
                out[b * DD + m] = c;                 // root_c
                out[BB * DD + b * DD + m] = h;       // root_h
            }
        }
    }
}

extern "C" void kernel_launch(void* const* d_in, const int* in_sizes, int n_in,
                              void* d_out, int out_size, void* d_ws, size_t ws_size,
                              hipStream_t stream) {
    (void)in_sizes; (void)n_in; (void)out_size; (void)ws_size;
    const float* inputs = (const float*)d_in[0];
    const float* W_ioux = (const float*)d_in[1];
    const float* b_ioux = (const float*)d_in[2];
    const float* W_iouh = (const float*)d_in[3];
    const float* b_iouh = (const float*)d_in[4];
    const float* W_fx = (const float*)d_in[5];
    const float* b_fx = (const float*)d_in[6];
    const float* W_fh = (const float*)d_in[7];
    const float* b_fh = (const float*)d_in[8];
    // d_in[9] children_idx unused: structure is the static full binary heap.

    char* ws = (char*)d_ws;
    short* xbf = (short*)(ws + OFF_XBF);
    short* hbf = (short*)(ws + OFF_HBF);
    float* cbuf = (float*)(ws + OFF_CBUF);
    short* wcat = (short*)(ws + OFF_WCAT);
    float* bias = (float*)(ws + OFF_BIAS);
    float* outp = (float*)d_out;

    prep_all<<<dim3(2048), dim3(256), 0, stream>>>(
        inputs, W_ioux, W_iouh, W_fx, W_fh, b_ioux, b_iouh, b_fx, b_fh,
        xbf, wcat, bias);

    // leaves: 512 row-tiles x 16 m-tiles; 64x16 blocks, 2 tasks/wave
    xproj<<<dim3(64, 16), dim3(256), 0, stream>>>(
        xbf, wcat, bias, hbf, cbuf, outp, 512);

    // internal levels d = 7 (128 nodes) .. d = 0 (root); gx capped at 32
    for (int d = 7; d >= 0; --d) {
        const int istart = 512 - (1 << (d + 1));
        const int ntasks = (1 << d) * 2;
        int gx = (ntasks + 3) / 4; if (gx > 32) gx = 32;
        level_h<<<dim3(gx, 16), dim3(256), 0, stream>>>(
            xbf, wcat, bias, hbf, cbuf, outp, istart, ntasks);
    }
}

// Round 12
// 123.786 us; speedup vs baseline: 1.4597x; 1.4597x over previous
//
#include <hip/hip_runtime.h>
#include <hip/hip_bf16.h>

// ChildSum Tree-LSTM, MI355X. B=32, N=511 full binary heap (children of i:
// 2i-511, 2i-512; leaves i<256; root 510). v12 = v10 skeleton, level_h
// reworked: one wave = one node (both 16-row b-halves) so each LDS B-fragment
// feeds 2-4 MFMAs (level GEMMs measured LDS-pipe bound at ~5% MfmaUtil).
// VGPR kept under the (256,2) 128-cap via K-chunked A prefetch (x:4ks, h:2ks)
// and afx folded into af0/af1 after the x phase (10 accs in h phase).
// Measured session facts:
//  - r7/r8: single-kernel cross-block sync ~13x slow (XCD L2 flush per fence).
//  - r9: exceeding launch_bounds VGPR cap -> scratch spill (WRITE_SIZE 10x).
//  - r11: global_load_lds staging of RE-READ weights bypasses L2 reuse
//    (FETCH 57MB/dispatch) -> reg-staged LDS writes for reused data.

#define NN 511
#define BB 32
#define DD 256

typedef __attribute__((ext_vector_type(8))) short short8;
typedef __attribute__((ext_vector_type(4))) short short4v;
typedef __attribute__((ext_vector_type(4))) float f32x4;

#define MFMA __builtin_amdgcn_mfma_f32_16x16x32_bf16

// ---- ws layout (bytes) ----
#define OFF_XBF   0UL            // [511*32][256] bf16 = 8,372,224
#define OFF_HBF   8372224UL      // [511*32][256] bf16 = 8,372,224
#define OFF_CBUF  16744448UL     // [511*32][256] f32  = 16,744,448
#define OFF_WCAT  33488896UL     // [1024][512] bf16   = 1,048,576 (rows i,o,u,f x256; cols 0:256 Wx, 256:512 Wh)
#define OFF_BIAS  34537472UL     // [1024] f32 = bx + bh
// total ~34.5 MB

__device__ __forceinline__ short f2bf(float f) {
    union { float f; unsigned int u; } v; v.f = f;
    unsigned int r = (v.u + 0x7FFFu + ((v.u >> 16) & 1u)) >> 16;  // RNE
    return (short)(unsigned short)r;
}
__device__ __forceinline__ float sigmf(float x) { return 1.0f / (1.0f + __expf(-x)); }
__device__ __forceinline__ float tanhc(float x) {
    x = fminf(fmaxf(x, -15.f), 15.f);
    float e = __expf(2.f * x);
    return (e - 1.f) / (e + 1.f);
}

// ---- merged prep: x -> bf16 node-major, weights -> wcat bf16, bias ----
__global__ void prep_all(const float* __restrict__ inp,
                         const float* __restrict__ Wix, const float* __restrict__ Wih,
                         const float* __restrict__ Wfx, const float* __restrict__ Wfh,
                         const float* __restrict__ bix, const float* __restrict__ bih,
                         const float* __restrict__ bfx, const float* __restrict__ bfh,
                         short* __restrict__ xbf, short* __restrict__ wcat,
                         float* __restrict__ bias) {
    const int tid = threadIdx.x;
    for (int v = blockIdx.x; v < 4088 + 2048; v += gridDim.x) {
        if (v < 4088) {                    // prep_x: 4088*256 == 511*32*64 float4s
            int idx = v * 256 + tid;
            int n = idx / (BB * 64);
            int rem = idx - n * (BB * 64);
            int b = rem >> 6;
            int c4 = rem & 63;
            float4 w = ((const float4*)(inp + ((long)b * NN + n) * DD))[c4];
            short4v sv = { f2bf(w.x), f2bf(w.y), f2bf(w.z), f2bf(w.w) };
            *(short4v*)(xbf + (long)idx * 4) = sv;
        } else {                           // prep_w: 2048*256 == 1024*512
            int t = (v - 4088) * 256 + tid;
            int row = t >> 9, c = t & 511;
            float w;
            if (c < 256) w = (row < 768) ? Wix[row * 256 + c] : Wfx[(row - 768) * 256 + c];
            else         w = (row < 768) ? Wih[row * 256 + (c - 256)]
                                         : Wfh[(row - 768) * 256 + (c - 256)];
            wcat[t] = f2bf(w);
            if (c == 0)
                bias[row] = (row < 768) ? (bix[row] + bih[row])
                                        : (bfx[row - 768] + bfh[row - 768]);
        }
    }
}

// MFMA 16x16x32 bf16 mapping (m89/m91-verified):
//   A[row=lane&15][k=(lane>>4)*8+j], B[k][col=lane&15], D[row=(lane>>4)*4+r][col=lane&15]

// Leaf-only x-projection + gate epilogue. Stages 3 streams x K=256 = 24 KiB LDS.
__global__ __launch_bounds__(256, 4) void xproj(
    const short* __restrict__ xbf, const short* __restrict__ wcat,
    const float* __restrict__ bias, short* __restrict__ hbf,
    float* __restrict__ cbuf, float* __restrict__ out) {
    __shared__ short lb[3 * 16 * 256];       // 24 KiB
    const int tid = threadIdx.x;
    const int mt = blockIdx.y;               // 16-col m-tile, 0..15
    for (int u = tid; u < 3 * 16 * 32; u += 256) {
        const int s = u >> 9;                // stream 0..2
        const int rr = (u >> 5) & 15;        // row in slice
        const int k = (u & 31) * 8;          // 0..255
        short8 v = *(const short8*)(wcat + ((long)(s * 256 + mt * 16 + rr) * 512 + k));
        *(short8*)(lb + (s * 16 + rr) * 256 + (k ^ ((rr & 7) << 3))) = v;
    }
    __syncthreads();

    const int lane = tid & 63;
    const int wid = tid >> 6;
    const int rt = blockIdx.x * 4 + wid;     // row-tile = leafnode*2 + bhalf
    if (rt >= 512) return;
    const int arow = lane & 15;
    const int kgrp = lane >> 4;
    const int node = rt >> 1;
    const int bh = rt & 1;
    const int m = mt * 16 + arow;
    const int swz = (arow & 7) << 3;

    const short* ap = xbf + ((long)rt * 16 + arow) * DD + kgrp * 8;
    short8 a[8];
#pragma unroll
    for (int ks = 0; ks < 8; ++ks) a[ks] = *(const short8*)(ap + ks * 32);

    f32x4 ai = {0.f, 0.f, 0.f, 0.f}, ao = ai, au = ai;
    const short* b0 = lb + (0 * 16 + arow) * 256;
    const short* b1 = lb + (1 * 16 + arow) * 256;
    const short* b2 = lb + (2 * 16 + arow) * 256;
#pragma unroll
    for (int ks = 0; ks < 8; ++ks) {
        const int ko = (ks * 32 + kgrp * 8) ^ swz;
        ai = MFMA(a[ks], *(const short8*)(b0 + ko), ai, 0, 0, 0);
        ao = MFMA(a[ks], *(const short8*)(b1 + ko), ao, 0, 0, 0);
        au = MFMA(a[ks], *(const short8*)(b2 + ko), au, 0, 0, 0);
    }

    const float bi = bias[m], bo = bias[256 + m], bu = bias[512 + m];
#pragma unroll
    for (int r = 0; r < 4; ++r) {
        const int b = bh * 16 + kgrp * 4 + r;
        const float iv = sigmf(ai[r] + bi);
        const float ov = sigmf(ao[r] + bo);
        const float uv = tanhc(au[r] + bu);
        const float c = iv * uv;
        const float h = ov * tanhc(c);
        const long rowg = (long)node * BB + b;
        cbuf[rowg * DD + m] = c;
        hbf[rowg * DD + m] = f2bf(h);
        out[2 * BB * DD + ((long)b * NN + node) * DD + m] = h;
    }
}

// Internal levels: one wave = one node, BOTH b-halves (B-fragment reuse 2-4x).
// K-chunked A prefetch bounds VGPR: x-phase 4-ks chunks, h-phase 2-ks chunks.
__global__ __launch_bounds__(256, 2) void level_h(
    const short* __restrict__ xbf, const short* __restrict__ wcat,
    const float* __restrict__ bias, short* __restrict__ hbf,
    float* __restrict__ cbuf, float* __restrict__ out, int istart, int ncount) {
    __shared__ short lb[4 * 16 * 512];       // 64 KiB
    const int tid = threadIdx.x;
    const int mt = blockIdx.y;
#pragma unroll
    for (int it = 0; it < 16; ++it) {        // reg-staged (r11: keep L2 reuse)
        const int u = it * 256 + tid;
        const int s = u >> 10;
        const int rr = (u >> 6) & 15;
        const int k = (u & 63) * 8;
        short8 v = *(const short8*)(wcat + ((long)(s * 256 + mt * 16 + rr) * 512 + k));
        *(short8*)(lb + (s * 16 + rr) * 512 + (k ^ ((rr & 7) << 3))) = v;
    }
    __syncthreads();

    const int lane = tid & 63;
    const int wid = tid >> 6;
    const int p = blockIdx.x * 4 + wid;      // node index within level
    if (p >= ncount) return;
    const int arow = lane & 15;
    const int kgrp = lane >> 4;
    const int node = istart + p;
    const int m = mt * 16 + arow;
    const int swz = (arow & 7) << 3;
    const int c0 = 2 * node - 511, c1 = 2 * node - 512;
    const short* b0 = lb + (0 * 16 + arow) * 512;
    const short* b1 = lb + (1 * 16 + arow) * 512;
    const short* b2 = lb + (2 * 16 + arow) * 512;
    const short* b3 = lb + (3 * 16 + arow) * 512;

    const f32x4 z = {0.f, 0.f, 0.f, 0.f};
    f32x4 ai[2] = {z, z}, ao[2] = {z, z}, au[2] = {z, z};
    f32x4 af0[2] = {z, z}, af1[2];

    // ---- x phase: K cols 0..255, 2 chunks of 4 ks; af0 doubles as afx ----
    const short* axb = xbf + (long)node * BB * DD + (long)arow * DD + kgrp * 8;
#pragma unroll
    for (int ch = 0; ch < 2; ++ch) {
        short8 a[2][4];
#pragma unroll
        for (int ks = 0; ks < 4; ++ks)
#pragma unroll
            for (int h2 = 0; h2 < 2; ++h2)
                a[h2][ks] = *(const short8*)(axb + h2 * 16 * DD + (ch * 4 + ks) * 32);
#pragma unroll
        for (int ks = 0; ks < 4; ++ks) {
            const int ko = ((ch * 4 + ks) * 32 + kgrp * 8) ^ swz;
            short8 wi = *(const short8*)(b0 + ko);
            short8 wo = *(const short8*)(b1 + ko);
            short8 wu = *(const short8*)(b2 + ko);
            short8 wf = *(const short8*)(b3 + ko);
#pragma unroll
            for (int h2 = 0; h2 < 2; ++h2) {
                ai[h2] = MFMA(a[h2][ks], wi, ai[h2], 0, 0, 0);
                ao[h2] = MFMA(a[h2][ks], wo, ao[h2], 0, 0, 0);
                au[h2] = MFMA(a[h2][ks], wu, au[h2], 0, 0, 0);
                af0[h2] = MFMA(a[h2][ks], wf, af0[h2], 0, 0, 0);   // afx
            }
        }
    }
    af1[0] = af0[0];   // fold x-contribution into both per-child f accs
    af1[1] = af0[1];

    // ---- h phase: K cols 256..511, 4 chunks of 2 ks ----
    const short* h0b = hbf + (long)c0 * BB * DD + (long)arow * DD + kgrp * 8;
    const short* h1b = hbf + (long)c1 * BB * DD + (long)arow * DD + kgrp * 8;
#pragma unroll
    for (int ch = 0; ch < 4; ++ch) {
        short8 a0[2][2], a1[2][2];
#pragma unroll
        for (int ks = 0; ks < 2; ++ks)
#pragma unroll
            for (int h2 = 0; h2 < 2; ++h2) {
                const long off = h2 * 16 * DD + (ch * 2 + ks) * 32;
                a0[h2][ks] = *(const short8*)(h0b + off);
                a1[h2][ks] = *(const short8*)(h1b + off);
            }
#pragma unroll
        for (int ks = 0; ks < 2; ++ks) {
            const int ko = 256 + (((ch * 2 + ks) * 32 + kgrp * 8) ^ swz);
            short8 wi = *(const short8*)(b0 + ko);
            short8 wo = *(const short8*)(b1 + ko);
            short8 wu = *(const short8*)(b2 + ko);
            short8 wf = *(const short8*)(b3 + ko);
#pragma unroll
            for (int h2 = 0; h2 < 2; ++h2) {
                ai[h2] = MFMA(a0[h2][ks], wi, ai[h2], 0, 0, 0);   // fp32 child-sum
                ai[h2] = MFMA(a1[h2][ks], wi, ai[h2], 0, 0, 0);
                ao[h2] = MFMA(a0[h2][ks], wo, ao[h2], 0, 0, 0);
                ao[h2] = MFMA(a1[h2][ks], wo, ao[h2], 0, 0, 0);
                au[h2] = MFMA(a0[h2][ks], wu, au[h2], 0, 0, 0);
                au[h2] = MFMA(a1[h2][ks], wu, au[h2], 0, 0, 0);
                af0[h2] = MFMA(a0[h2][ks], wf, af0[h2], 0, 0, 0); // per-child f
                af1[h2] = MFMA(a1[h2][ks], wf, af1[h2], 0, 0, 0);
            }
        }
    }

    const float bi = bias[m], bo = bias[256 + m], bu = bias[512 + m], bf = bias[768 + m];
#pragma unroll
    for (int h2 = 0; h2 < 2; ++h2)
#pragma unroll
        for (int r = 0; r < 4; ++r) {
            const int b = h2 * 16 + kgrp * 4 + r;
            const float iv = sigmf(ai[h2][r] + bi);
            const float ov = sigmf(ao[h2][r] + bo);
            const float uv = tanhc(au[h2][r] + bu);
            const float f0 = sigmf(af0[h2][r] + bf);
            const float f1 = sigmf(af1[h2][r] + bf);
            const float cc0 = cbuf[((long)c0 * BB + b) * DD + m];
            const float cc1 = cbuf[((long)c1 * BB + b) * DD + m];
            const float c = iv * uv + f0 * cc0 + f1 * cc1;
            const float h = ov * tanhc(c);
            const long rowg = (long)node * BB + b;
            cbuf[rowg * DD + m] = c;
            hbf[rowg * DD + m] = f2bf(h);
            out[2 * BB * DD + ((long)b * NN + node) * DD + m] = h;
            if (node == NN - 1) {
                out[b * DD + m] = c;                 // root_c
                out[BB * DD + b * DD + m] = h;       // root_h
            }
        }
}

extern "C" void kernel_launch(void* const* d_in, const int* in_sizes, int n_in,
                              void* d_out, int out_size, void* d_ws, size_t ws_size,
                              hipStream_t stream) {
    (void)in_sizes; (void)n_in; (void)out_size; (void)ws_size;
    const float* inputs = (const float*)d_in[0];
    const float* W_ioux = (const float*)d_in[1];
    const float* b_ioux = (const float*)d_in[2];
    const float* W_iouh = (const float*)d_in[3];
    const float* b_iouh = (const float*)d_in[4];
    const float* W_fx = (const float*)d_in[5];
    const float* b_fx = (const float*)d_in[6];
    const float* W_fh = (const float*)d_in[7];
    const float* b_fh = (const float*)d_in[8];
    // d_in[9] children_idx unused: structure is the static full binary heap.

    char* ws = (char*)d_ws;
    short* xbf = (short*)(ws + OFF_XBF);
    short* hbf = (short*)(ws + OFF_HBF);
    float* cbuf = (float*)(ws + OFF_CBUF);
    short* wcat = (short*)(ws + OFF_WCAT);
    float* bias = (float*)(ws + OFF_BIAS);
    float* outp = (float*)d_out;

    prep_all<<<dim3(2048), dim3(256), 0, stream>>>(
        inputs, W_ioux, W_iouh, W_fx, W_fh, b_ioux, b_iouh, b_fx, b_fh,
        xbf, wcat, bias);

    // leaves: 512 row-tiles x 16 m-tiles
    xproj<<<dim3(128, 16), dim3(256), 0, stream>>>(xbf, wcat, bias, hbf, cbuf, outp);

    // internal levels d = 7 (128 nodes) .. d = 0 (root); 1 node per wave
    for (int d = 7; d >= 0; --d) {
        const int istart = 512 - (1 << (d + 1));
        const int ncount = 1 << d;
        level_h<<<dim3((ncount + 3) / 4, 16), dim3(256), 0, stream>>>(
            xbf, wcat, bias, hbf, cbuf, outp, istart, ncount);
    }
}

// Round 13
// 108.733 us; speedup vs baseline: 1.6618x; 1.1384x over previous
//
#include <hip/hip_runtime.h>
#include <hip/hip_bf16.h>

// ChildSum Tree-LSTM, MI355X. B=32, N=511 full binary heap (children of i:
// 2i-511, 2i-512; leaves i<256; root 510). v13 = v10 (proven 100us) with
// level_h moved to 512-thread blocks: same 64 KiB LDS -> 2 blocks/CU but
// 16 waves/CU (was 8). Body byte-identical; only geometry changes.
// Measured session facts:
//  - r7/r8: single-kernel cross-block sync ~13x slow (XCD L2 flush per fence).
//  - r9: exceeding launch_bounds VGPR cap -> scratch spill (WRITE_SIZE 10x).
//  - r9/r12: B-reuse via multi-subtile waves regresses (chunked A-prefetch
//    serializes latency exposures); whole-K A prefetch + 1 task/wave wins.
//  - r11: global_load_lds staging of RE-READ weights bypasses L2 reuse.

#define NN 511
#define BB 32
#define DD 256

typedef __attribute__((ext_vector_type(8))) short short8;
typedef __attribute__((ext_vector_type(4))) short short4v;
typedef __attribute__((ext_vector_type(4))) float f32x4;

#define MFMA __builtin_amdgcn_mfma_f32_16x16x32_bf16

// ---- ws layout (bytes) ----
#define OFF_XBF   0UL            // [511*32][256] bf16 = 8,372,224
#define OFF_HBF   8372224UL      // [511*32][256] bf16 = 8,372,224
#define OFF_CBUF  16744448UL     // [511*32][256] f32  = 16,744,448
#define OFF_WCAT  33488896UL     // [1024][512] bf16   = 1,048,576 (rows i,o,u,f x256; cols 0:256 Wx, 256:512 Wh)
#define OFF_BIAS  34537472UL     // [1024] f32 = bx + bh
// total ~34.5 MB

__device__ __forceinline__ short f2bf(float f) {
    union { float f; unsigned int u; } v; v.f = f;
    unsigned int r = (v.u + 0x7FFFu + ((v.u >> 16) & 1u)) >> 16;  // RNE
    return (short)(unsigned short)r;
}
__device__ __forceinline__ float sigmf(float x) { return 1.0f / (1.0f + __expf(-x)); }
__device__ __forceinline__ float tanhc(float x) {
    x = fminf(fmaxf(x, -15.f), 15.f);
    float e = __expf(2.f * x);
    return (e - 1.f) / (e + 1.f);
}

// ---- merged prep: x -> bf16 node-major, weights -> wcat bf16, bias ----
__global__ void prep_all(const float* __restrict__ inp,
                         const float* __restrict__ Wix, const float* __restrict__ Wih,
                         const float* __restrict__ Wfx, const float* __restrict__ Wfh,
                         const float* __restrict__ bix, const float* __restrict__ bih,
                         const float* __restrict__ bfx, const float* __restrict__ bfh,
                         short* __restrict__ xbf, short* __restrict__ wcat,
                         float* __restrict__ bias) {
    const int tid = threadIdx.x;
    for (int v = blockIdx.x; v < 4088 + 2048; v += gridDim.x) {
        if (v < 4088) {                    // prep_x: 4088*256 == 511*32*64 float4s
            int idx = v * 256 + tid;
            int n = idx / (BB * 64);
            int rem = idx - n * (BB * 64);
            int b = rem >> 6;
            int c4 = rem & 63;
            float4 w = ((const float4*)(inp + ((long)b * NN + n) * DD))[c4];
            short4v sv = { f2bf(w.x), f2bf(w.y), f2bf(w.z), f2bf(w.w) };
            *(short4v*)(xbf + (long)idx * 4) = sv;
        } else {                           // prep_w: 2048*256 == 1024*512
            int t = (v - 4088) * 256 + tid;
            int row = t >> 9, c = t & 511;
            float w;
            if (c < 256) w = (row < 768) ? Wix[row * 256 + c] : Wfx[(row - 768) * 256 + c];
            else         w = (row < 768) ? Wih[row * 256 + (c - 256)]
                                         : Wfh[(row - 768) * 256 + (c - 256)];
            wcat[t] = f2bf(w);
            if (c == 0)
                bias[row] = (row < 768) ? (bix[row] + bih[row])
                                        : (bfx[row - 768] + bfh[row - 768]);
        }
    }
}

// MFMA 16x16x32 bf16 mapping (m89/m91-verified):
//   A[row=lane&15][k=(lane>>4)*8+j], B[k][col=lane&15], D[row=(lane>>4)*4+r][col=lane&15]

// Leaf-only x-projection + gate epilogue. Stages 3 streams x K=256 = 24 KiB LDS.
__global__ __launch_bounds__(256, 4) void xproj(
    const short* __restrict__ xbf, const short* __restrict__ wcat,
    const float* __restrict__ bias, short* __restrict__ hbf,
    float* __restrict__ cbuf, float* __restrict__ out) {
    __shared__ short lb[3 * 16 * 256];       // 24 KiB
    const int tid = threadIdx.x;
    const int mt = blockIdx.y;               // 16-col m-tile, 0..15
    for (int u = tid; u < 3 * 16 * 32; u += 256) {
        const int s = u >> 9;                // stream 0..2
        const int rr = (u >> 5) & 15;        // row in slice
        const int k = (u & 31) * 8;          // 0..255
        short8 v = *(const short8*)(wcat + ((long)(s * 256 + mt * 16 + rr) * 512 + k));
        *(short8*)(lb + (s * 16 + rr) * 256 + (k ^ ((rr & 7) << 3))) = v;
    }
    __syncthreads();

    const int lane = tid & 63;
    const int wid = tid >> 6;
    const int rt = blockIdx.x * 4 + wid;     // row-tile = leafnode*2 + bhalf
    if (rt >= 512) return;
    const int arow = lane & 15;
    const int kgrp = lane >> 4;
    const int node = rt >> 1;
    const int bh = rt & 1;
    const int m = mt * 16 + arow;
    const int swz = (arow & 7) << 3;

    const short* ap = xbf + ((long)rt * 16 + arow) * DD + kgrp * 8;
    short8 a[8];
#pragma unroll
    for (int ks = 0; ks < 8; ++ks) a[ks] = *(const short8*)(ap + ks * 32);

    f32x4 ai = {0.f, 0.f, 0.f, 0.f}, ao = ai, au = ai;
    const short* b0 = lb + (0 * 16 + arow) * 256;
    const short* b1 = lb + (1 * 16 + arow) * 256;
    const short* b2 = lb + (2 * 16 + arow) * 256;
#pragma unroll
    for (int ks = 0; ks < 8; ++ks) {
        const int ko = (ks * 32 + kgrp * 8) ^ swz;
        ai = MFMA(a[ks], *(const short8*)(b0 + ko), ai, 0, 0, 0);
        ao = MFMA(a[ks], *(const short8*)(b1 + ko), ao, 0, 0, 0);
        au = MFMA(a[ks], *(const short8*)(b2 + ko), au, 0, 0, 0);
    }

    const float bi = bias[m], bo = bias[256 + m], bu = bias[512 + m];
#pragma unroll
    for (int r = 0; r < 4; ++r) {
        const int b = bh * 16 + kgrp * 4 + r;
        const float iv = sigmf(ai[r] + bi);
        const float ov = sigmf(ao[r] + bo);
        const float uv = tanhc(au[r] + bu);
        const float c = iv * uv;
        const float h = ov * tanhc(c);
        const long rowg = (long)node * BB + b;
        cbuf[rowg * DD + m] = c;
        hbf[rowg * DD + m] = f2bf(h);
        out[2 * BB * DD + ((long)b * NN + node) * DD + m] = h;
    }
}

// Internal levels: fused K=512 GEMM ([x | h]), 64 KiB LDS, fused epilogue.
// 512-thread blocks: 2 blocks/CU (LDS) x 8 waves = 16 waves/CU (v10 had 8).
__global__ __launch_bounds__(512, 4) void level_h(
    const short* __restrict__ xbf, const short* __restrict__ wcat,
    const float* __restrict__ bias, short* __restrict__ hbf,
    float* __restrict__ cbuf, float* __restrict__ out, int istart, int ntasks) {
    __shared__ short lb[4 * 16 * 512];       // 64 KiB
    const int tid = threadIdx.x;
    const int mt = blockIdx.y;
    // stage full K=512 weight slice, XOR-swizzled within each 512-elem row
#pragma unroll
    for (int it = 0; it < 8; ++it) {
        const int u = it * 512 + tid;        // short8 index 0..4095
        const int s = u >> 10;               // stream 0..3
        const int r = (u >> 6) & 15;         // row in slice
        const int k = (u & 63) * 8;          // 0..511
        short8 v = *(const short8*)(wcat + ((long)(s * 256 + mt * 16 + r) * 512 + k));
        *(short8*)(lb + (s * 16 + r) * 512 + (k ^ ((r & 7) << 3))) = v;
    }
    __syncthreads();

    const int lane = tid & 63;
    const int wid = tid >> 6;                // 0..7
    const int rt = blockIdx.x * 8 + wid;
    if (rt >= ntasks) return;
    const int arow = lane & 15;
    const int kgrp = lane >> 4;
    const int node = istart + (rt >> 1);
    const int bh = rt & 1;
    const int m = mt * 16 + arow;
    const int swz = (arow & 7) << 3;
    const int c0 = 2 * node - 511, c1 = 2 * node - 512;
    const short* b0 = lb + (0 * 16 + arow) * 512;
    const short* b1 = lb + (1 * 16 + arow) * 512;
    const short* b2 = lb + (2 * 16 + arow) * 512;
    const short* b3 = lb + (3 * 16 + arow) * 512;

    f32x4 ai = {0.f, 0.f, 0.f, 0.f}, ao = ai, au = ai, afx = ai, af0 = ai, af1 = ai;

    // ---- x phase: K cols 0..255, whole-K A prefetch (8 x short8) ----
    {
        const short* ap = xbf + ((long)(node * BB + bh * 16) + arow) * DD + kgrp * 8;
        short8 a[8];
#pragma unroll
        for (int ks = 0; ks < 8; ++ks) a[ks] = *(const short8*)(ap + ks * 32);
#pragma unroll
        for (int ks = 0; ks < 8; ++ks) {
            const int ko = (ks * 32 + kgrp * 8) ^ swz;
            ai = MFMA(a[ks], *(const short8*)(b0 + ko), ai, 0, 0, 0);
            ao = MFMA(a[ks], *(const short8*)(b1 + ko), ao, 0, 0, 0);
            au = MFMA(a[ks], *(const short8*)(b2 + ko), au, 0, 0, 0);
            afx = MFMA(a[ks], *(const short8*)(b3 + ko), afx, 0, 0, 0);
        }
    }
    // ---- h phase: K cols 256..511, both children whole-K (16 x short8) ----
    {
        const short* ap0 = hbf + ((long)(c0 * BB + bh * 16) + arow) * DD + kgrp * 8;
        const short* ap1 = hbf + ((long)(c1 * BB + bh * 16) + arow) * DD + kgrp * 8;
        short8 a0[8], a1[8];
#pragma unroll
        for (int ks = 0; ks < 8; ++ks) {
            a0[ks] = *(const short8*)(ap0 + ks * 32);
            a1[ks] = *(const short8*)(ap1 + ks * 32);
        }
#pragma unroll
        for (int ks = 0; ks < 8; ++ks) {
            const int ko = 256 + ((ks * 32 + kgrp * 8) ^ swz);
            short8 wi = *(const short8*)(b0 + ko);
            short8 wo = *(const short8*)(b1 + ko);
            short8 wu = *(const short8*)(b2 + ko);
            short8 wf = *(const short8*)(b3 + ko);
            ai = MFMA(a0[ks], wi, ai, 0, 0, 0);   // fp32 child-sum via accumulation
            ai = MFMA(a1[ks], wi, ai, 0, 0, 0);
            ao = MFMA(a0[ks], wo, ao, 0, 0, 0);
            ao = MFMA(a1[ks], wo, ao, 0, 0, 0);
            au = MFMA(a0[ks], wu, au, 0, 0, 0);
            au = MFMA(a1[ks], wu, au, 0, 0, 0);
            af0 = MFMA(a0[ks], wf, af0, 0, 0, 0); // per-child forget gates
            af1 = MFMA(a1[ks], wf, af1, 0, 0, 0);
        }
    }

    const float bi = bias[m], bo = bias[256 + m], bu = bias[512 + m], bf = bias[768 + m];
#pragma unroll
    for (int r = 0; r < 4; ++r) {
        const int b = bh * 16 + kgrp * 4 + r;
        const float iv = sigmf(ai[r] + bi);
        const float ov = sigmf(ao[r] + bo);
        const float uv = tanhc(au[r] + bu);
        const float f0 = sigmf(afx[r] + af0[r] + bf);
        const float f1 = sigmf(afx[r] + af1[r] + bf);
        const float cc0 = cbuf[((long)c0 * BB + b) * DD + m];
        const float cc1 = cbuf[((long)c1 * BB + b) * DD + m];
        const float c = iv * uv + f0 * cc0 + f1 * cc1;
        const float h = ov * tanhc(c);
        const long rowg = (long)node * BB + b;
        cbuf[rowg * DD + m] = c;
        hbf[rowg * DD + m] = f2bf(h);
        out[2 * BB * DD + ((long)b * NN + node) * DD + m] = h;
        if (node == NN - 1) {
            out[b * DD + m] = c;                 // root_c
            out[BB * DD + b * DD + m] = h;       // root_h
        }
    }
}

extern "C" void kernel_launch(void* const* d_in, const int* in_sizes, int n_in,
                              void* d_out, int out_size, void* d_ws, size_t ws_size,
                              hipStream_t stream) {
    (void)in_sizes; (void)n_in; (void)out_size; (void)ws_size;
    const float* inputs = (const float*)d_in[0];
    const float* W_ioux = (const float*)d_in[1];
    const float* b_ioux = (const float*)d_in[2];
    const float* W_iouh = (const float*)d_in[3];
    const float* b_iouh = (const float*)d_in[4];
    const float* W_fx = (const float*)d_in[5];
    const float* b_fx = (const float*)d_in[6];
    const float* W_fh = (const float*)d_in[7];
    const float* b_fh = (const float*)d_in[8];
    // d_in[9] children_idx unused: structure is the static full binary heap.

    char* ws = (char*)d_ws;
    short* xbf = (short*)(ws + OFF_XBF);
    short* hbf = (short*)(ws + OFF_HBF);
    float* cbuf = (float*)(ws + OFF_CBUF);
    short* wcat = (short*)(ws + OFF_WCAT);
    float* bias = (float*)(ws + OFF_BIAS);
    float* outp = (float*)d_out;

    prep_all<<<dim3(2048), dim3(256), 0, stream>>>(
        inputs, W_ioux, W_iouh, W_fx, W_fh, b_ioux, b_iouh, b_fx, b_fh,
        xbf, wcat, bias);

    // leaves: 512 row-tiles x 16 m-tiles
    xproj<<<dim3(128, 16), dim3(256), 0, stream>>>(xbf, wcat, bias, hbf, cbuf, outp);

    // internal levels d = 7 (128 nodes) .. d = 0 (root); 512-thread blocks
    for (int d = 7; d >= 0; --d) {
        const int istart = 512 - (1 << (d + 1));
        const int ntasks = (1 << d) * 2;
        level_h<<<dim3((ntasks + 7) / 8, 16), dim3(512), 0, stream>>>(
            xbf, wcat, bias, hbf, cbuf, outp, istart, ntasks);
    }
}